// Round 9
// baseline (27015.384 us; speedup 1.0000x reference)
//
#include <hip/hip_runtime.h>
#include <hip/hip_bf16.h>
#include <cstdint>

using bf16 = __hip_bfloat16;
#define DI __device__ __forceinline__

DI float b2f(bf16 v){ return __bfloat162float(v); }
DI float us2f(unsigned short u){ bf16 t; *reinterpret_cast<unsigned short*>(&t) = u; return __bfloat162float(t); }

// R9: OUTPUT IS FLOAT32 (reference computes in f32; harness reads d_out as f32).
// R0-R8 wrote bf16 into the f32 buffer -> position-scrambled readback, which is
// the only theory consistent with R8's all-diagnostics-pass + decorrelated output.
// Pipeline identical to R8 otherwise. LDS atomics only. Diagnostics retained.

// ---------------- dtype detection on pos (~N(0,1)) ----------------
__global__ void kdetect(const unsigned short* __restrict__ pos_u, int* __restrict__ flag){
  __shared__ int cE, cO;
  if (threadIdx.x == 0){ cE = 0; cO = 0; }
  __syncthreads();
  int pe = 0, po = 0;
  for (int i = threadIdx.x; i < 2048; i += 256){
    float ve = fabsf(us2f(pos_u[2*i]));
    float vo = fabsf(us2f(pos_u[2*i + 1]));
    if (ve > 1e-4f && ve < 50.f) pe++;
    if (vo > 1e-4f && vo < 50.f) po++;
  }
  atomicAdd(&cE, pe);
  atomicAdd(&cO, po);
  __syncthreads();
  if (threadIdx.x == 0)
    flag[0] = (2*cE < cO) ? 1 : 0;   // 1 => inputs are f32
}

// ---------------- normalize all float inputs to f32 ----------------
struct CEnt { const void* s; float* d; int n; };
struct CTab { CEnt e[39]; };
__global__ void kconv(CTab tab, const int* __restrict__ flag){
  CEnt en = tab.e[blockIdx.y];
  const bool isf32 = (flag[0] != 0);
  for (int i = blockIdx.x*256 + threadIdx.x; i < en.n; i += gridDim.x*256)
    en.d[i] = isf32 ? ((const float*)en.s)[i] : b2f(((const bf16*)en.s)[i]);
}

// ---------------- graph partition ----------------
__global__ void kgptr(const int* __restrict__ batch, int Nn, int* __restrict__ gptr){
  int g = threadIdx.x;
  if (g > 8) return;
  if (g == 8){ gptr[8] = Nn; return; }
  int lo = 0, hi = Nn;
  while (lo < hi){ int mid = (lo + hi) >> 1; if (batch[mid] < g) lo = mid + 1; else hi = mid; }
  gptr[g] = lo;
}

// ---------------- per-graph heatmap column sums ----------------
__global__ void khs(const float* __restrict__ hmf, const int* __restrict__ gptr,
                    float* __restrict__ hs){
  int g = blockIdx.x;
  int lane = threadIdx.x % 24, slice = threadIdx.x / 24;
  __shared__ float part[10][24];
  if (threadIdx.x < 240){
    int s = gptr[g], e = gptr[g+1];
    float acc = 0.f;
    for (int n = s + slice; n < e; n += 10) acc += hmf[(size_t)n*24 + lane];
    part[slice][lane] = acc;
  }
  __syncthreads();
  if (threadIdx.x < 24){
    float a = 0.f;
    for (int i = 0; i < 10; ++i) a += part[i][threadIdx.x];
    hs[g*24 + threadIdx.x] = a;
  }
}

// ---------------- single-block counting sort of edges by dst ----------------
#define WIN 8192
__global__ void ksort(const int* __restrict__ dst, int E, int Nn,
                      int* __restrict__ cnt, int* __restrict__ rp, int* __restrict__ eidx){
  __shared__ int win[WIN];
  __shared__ int buf[256];
  __shared__ int carry;
  int t = threadIdx.x;
  for (int base = 0; base < Nn; base += WIN){
    for (int i = t; i < WIN; i += 256) win[i] = 0;
    __syncthreads();
    for (int e = t; e < E; e += 256){
      int d = dst[e] - base;
      if (d >= 0 && d < WIN) atomicAdd(&win[d], 1);
    }
    __syncthreads();
    int lim = Nn - base; if (lim > WIN) lim = WIN;
    for (int i = t; i < lim; i += 256) cnt[base + i] = win[i];
    __syncthreads();
  }
  if (t == 0) carry = 0;
  __syncthreads();
  for (int base = 0; base < Nn; base += 256){
    int v = (base + t < Nn) ? cnt[base + t] : 0;
    buf[t] = v;
    __syncthreads();
    for (int off = 1; off < 256; off <<= 1){
      int x = (t >= off) ? buf[t - off] : 0;
      __syncthreads();
      buf[t] += x;
      __syncthreads();
    }
    if (base + t < Nn) rp[base + t] = carry + buf[t] - v;
    __syncthreads();
    if (t == 255) carry += buf[255];
    __syncthreads();
  }
  if (t == 0) rp[Nn] = carry;
  __syncthreads();
  for (int base = 0; base < Nn; base += WIN){
    for (int i = t; i < WIN; i += 256) win[i] = 0;
    __syncthreads();
    for (int e = t; e < E; e += 256){
      int d = dst[e] - base;
      if (d >= 0 && d < WIN){
        int lr = atomicAdd(&win[d], 1);
        eidx[rp[base + d] + lr] = e;
      }
    }
    __syncthreads();
  }
}

// ---------------- layer-1 stats-only pass ----------------
template<int CIN, int C, int MODE>
__launch_bounds__(256)
__global__ void kstats1(const float* __restrict__ W1, const float* __restrict__ b1,
                        const float* __restrict__ in0, const float* __restrict__ posf,
                        const float* __restrict__ featf, const int* __restrict__ src,
                        const int* __restrict__ dst, int E, float* __restrict__ statp){
  constexpr int NP = C / 64;
  constexpr int CP = CIN / 2;
  __shared__ float A1[32][CIN + 1];
  __shared__ int Si[32], Sj[32];
  __shared__ float red[16][64];
  int t = threadIdx.x, el = t & 15, grp = t >> 4;
  float sv[NP][4], qv[NP][4];
  #pragma unroll
  for (int p = 0; p < NP; ++p)
    #pragma unroll
    for (int i = 0; i < 4; ++i){ sv[p][i] = 0.f; qv[p][i] = 0.f; }

  int ntiles = (E + 31) / 32;
  for (int tt = blockIdx.x; tt < ntiles; tt += gridDim.x){
    int tile = tt * 32;
    int nrows = E - tile; if (nrows > 32) nrows = 32;
    __syncthreads();
    if (t < 32){
      if (t < nrows){ Si[t] = dst[tile + t]; Sj[t] = src[tile + t]; }
      else { Si[t] = 0; Sj[t] = 0; }
    }
    __syncthreads();
    for (int idx = t; idx < 32*CIN; idx += 256){
      int r = idx / CIN, k = idx - r*CIN;
      float v = 0.f;
      if (r < nrows){
        if constexpr (MODE == 0){
          int i = Si[r], j = Sj[r];
          v = (k < CP) ? in0[(size_t)i*CP + k]
                       : in0[(size_t)j*CP + (k-CP)] - in0[(size_t)i*CP + (k-CP)];
        } else {
          int i = Si[r], j = Sj[r];
          int c = (k < CP) ? k : (k - CP);
          float vi = (c < 3) ? posf[(size_t)i*3 + c] : featf[(size_t)i*61 + (c-3)];
          if (k < CP) v = vi;
          else {
            float vj = (c < 3) ? posf[(size_t)j*3 + c] : featf[(size_t)j*61 + (c-3)];
            v = vj - vi;
          }
        }
      }
      A1[r][k] = v;
    }
    __syncthreads();
    #pragma unroll
    for (int p = 0; p < NP; ++p){
      int c = p*64 + grp*4;
      float acc[2][4];
      #pragma unroll
      for (int i = 0; i < 4; ++i){ float b = b1[c+i]; acc[0][i] = b; acc[1][i] = b; }
      #pragma unroll 4
      for (int k = 0; k < CIN; ++k){
        float4 w = *reinterpret_cast<const float4*>(&W1[(size_t)k*C + c]);
        float a0 = A1[el][k], a1 = A1[el+16][k];
        acc[0][0] = fmaf(a0, w.x, acc[0][0]); acc[0][1] = fmaf(a0, w.y, acc[0][1]);
        acc[0][2] = fmaf(a0, w.z, acc[0][2]); acc[0][3] = fmaf(a0, w.w, acc[0][3]);
        acc[1][0] = fmaf(a1, w.x, acc[1][0]); acc[1][1] = fmaf(a1, w.y, acc[1][1]);
        acc[1][2] = fmaf(a1, w.z, acc[1][2]); acc[1][3] = fmaf(a1, w.w, acc[1][3]);
      }
      #pragma unroll
      for (int q = 0; q < 2; ++q){
        int row = el + q*16;
        if (row < nrows){
          #pragma unroll
          for (int i = 0; i < 4; ++i){
            float v = fmaxf(acc[q][i], 0.f);
            sv[p][i] += v; qv[p][i] += v*v;
          }
        }
      }
    }
  }
  for (int p = 0; p < NP; ++p){
    __syncthreads();
    #pragma unroll
    for (int i = 0; i < 4; ++i) red[el][grp*4 + i] = sv[p][i];
    __syncthreads();
    if (t < 64){
      float a = 0.f;
      for (int e2 = 0; e2 < 16; ++e2) a += red[e2][t];
      statp[(size_t)blockIdx.x*2*C + p*64 + t] = a;
    }
    __syncthreads();
    #pragma unroll
    for (int i = 0; i < 4; ++i) red[el][grp*4 + i] = qv[p][i];
    __syncthreads();
    if (t < 64){
      float a = 0.f;
      for (int e2 = 0; e2 < 16; ++e2) a += red[e2][t];
      statp[(size_t)blockIdx.x*2*C + C + p*64 + t] = a;
    }
  }
}

// ---------------- stats reduce + BN finalize ----------------
__global__ void kstatred(const float* __restrict__ statp, int nblk, int C,
                         float* __restrict__ gs, float* __restrict__ gq){
  int c = blockIdx.x;
  float s = 0.f, q = 0.f;
  for (int b = threadIdx.x; b < nblk; b += 256){
    s += statp[(size_t)b*2*C + c];
    q += statp[(size_t)b*2*C + C + c];
  }
  __shared__ float ls[256], lq[256];
  ls[threadIdx.x] = s; lq[threadIdx.x] = q;
  __syncthreads();
  for (int o = 128; o; o >>= 1){
    if (threadIdx.x < o){ ls[threadIdx.x] += ls[threadIdx.x+o]; lq[threadIdx.x] += lq[threadIdx.x+o]; }
    __syncthreads();
  }
  if (threadIdx.x == 0){ gs[c] = ls[0]; gq[c] = lq[0]; }
}
__global__ void finalize_bn(const float* __restrict__ gs, const float* __restrict__ gq,
                            const float* __restrict__ g, const float* __restrict__ be,
                            float invR, float* __restrict__ sc, float* __restrict__ sh){
  int c = threadIdx.x;
  float m  = gs[c] * invR;
  float va = gq[c] * invR - m*m;
  float s  = g[c] * rsqrtf(va + 1e-5f);
  sc[c] = s;
  sh[c] = be[c] - m*s;
}

// ---------------- fused GCU ----------------
template<int CIN, int C, int TE, int MODE>
__launch_bounds__(256)
__global__ void kfused(const float* __restrict__ W1, const float* __restrict__ b1,
                       const float* __restrict__ W2, const float* __restrict__ b2,
                       const float* __restrict__ sc1, const float* __restrict__ sh1,
                       const float* __restrict__ in0, const float* __restrict__ posf,
                       const float* __restrict__ featf,
                       const int* __restrict__ src, const int* __restrict__ dst,
                       const int* __restrict__ eidx, const int* __restrict__ rp,
                       float* __restrict__ nodemax, float* __restrict__ statp)
{
  constexpr int NT  = 16;
  constexpr int EPL = TE / 16;
  constexpr int NP  = C / 64;
  constexpr int CP  = CIN / 2;
  __shared__ float A1[TE][CIN + 1];
  __shared__ float H1[TE][C + 1];
  __shared__ float NM[NT][C];
  __shared__ float red[16][64];
  __shared__ int Si[TE], Sj[TE];
  float* H2 = &A1[0][0];

  int t = threadIdx.x, el = t & 15, grp = t >> 4;
  int n0 = blockIdx.x * NT;
  int e_begin = rp[n0];
  int e_end   = rp[n0 + NT];

  for (int i = t; i < NT*C; i += 256) (&NM[0][0])[i] = -INFINITY;

  float s2[NP][4], q2[NP][4];
  #pragma unroll
  for (int p = 0; p < NP; ++p)
    #pragma unroll
    for (int i = 0; i < 4; ++i){ s2[p][i] = 0.f; q2[p][i] = 0.f; }

  for (int tile = e_begin; tile < e_end; tile += TE){
    int nrows = e_end - tile; if (nrows > TE) nrows = TE;
    __syncthreads();
    if (t < TE){
      if (t < nrows){ int e = eidx[tile + t]; Si[t] = dst[e]; Sj[t] = src[e]; }
      else { Si[t] = 0; Sj[t] = 0; }
    }
    __syncthreads();
    for (int idx = t; idx < TE*CIN; idx += 256){
      int r = idx / CIN, k = idx - r*CIN;
      float v = 0.f;
      if (r < nrows){
        if constexpr (MODE == 0){
          int i = Si[r], j = Sj[r];
          v = (k < CP) ? in0[(size_t)i*CP + k]
                       : in0[(size_t)j*CP + (k-CP)] - in0[(size_t)i*CP + (k-CP)];
        } else {
          int i = Si[r], j = Sj[r];
          int c = (k < CP) ? k : (k - CP);
          float vi = (c < 3) ? posf[(size_t)i*3 + c] : featf[(size_t)i*61 + (c-3)];
          if (k < CP) v = vi;
          else {
            float vj = (c < 3) ? posf[(size_t)j*3 + c] : featf[(size_t)j*61 + (c-3)];
            v = vj - vi;
          }
        }
      }
      A1[r][k] = v;
    }
    __syncthreads();
    #pragma unroll
    for (int p = 0; p < NP; ++p){
      int c = p*64 + grp*4;
      float acc[EPL][4];
      #pragma unroll
      for (int i = 0; i < 4; ++i){
        float b = b1[c+i];
        #pragma unroll
        for (int q = 0; q < EPL; ++q) acc[q][i] = b;
      }
      #pragma unroll 4
      for (int k = 0; k < CIN; ++k){
        float4 w = *reinterpret_cast<const float4*>(&W1[(size_t)k*C + c]);
        #pragma unroll
        for (int q = 0; q < EPL; ++q){
          float a = A1[el + q*16][k];
          acc[q][0] = fmaf(a, w.x, acc[q][0]); acc[q][1] = fmaf(a, w.y, acc[q][1]);
          acc[q][2] = fmaf(a, w.z, acc[q][2]); acc[q][3] = fmaf(a, w.w, acc[q][3]);
        }
      }
      #pragma unroll
      for (int q = 0; q < EPL; ++q){
        int row = el + q*16;
        if (row < nrows){
          #pragma unroll
          for (int i = 0; i < 4; ++i)
            H1[row][c+i] = fmaxf(acc[q][i], 0.f) * sc1[c+i] + sh1[c+i];
        }
      }
    }
    __syncthreads();
    #pragma unroll
    for (int p = 0; p < NP; ++p){
      int c = p*64 + grp*4;
      float acc[EPL][4];
      #pragma unroll
      for (int i = 0; i < 4; ++i){
        float b = b2[c+i];
        #pragma unroll
        for (int q = 0; q < EPL; ++q) acc[q][i] = b;
      }
      #pragma unroll 4
      for (int k = 0; k < C; ++k){
        float4 w = *reinterpret_cast<const float4*>(&W2[(size_t)k*C + c]);
        #pragma unroll
        for (int q = 0; q < EPL; ++q){
          float a = H1[el + q*16][k];
          acc[q][0] = fmaf(a, w.x, acc[q][0]); acc[q][1] = fmaf(a, w.y, acc[q][1]);
          acc[q][2] = fmaf(a, w.z, acc[q][2]); acc[q][3] = fmaf(a, w.w, acc[q][3]);
        }
      }
      #pragma unroll
      for (int q = 0; q < EPL; ++q){
        int row = el + q*16;
        if (row < nrows){
          #pragma unroll
          for (int i = 0; i < 4; ++i){
            float v = fmaxf(acc[q][i], 0.f);
            s2[p][i] += v; q2[p][i] += v*v;
            H2[row*(C+1) + c + i] = v;
          }
        }
      }
    }
    __syncthreads();
    for (int idx = t; idx < NT*C; idx += 256){
      int ln = idx / C, c = idx - ln*C;
      int n = n0 + ln;
      int lo = rp[n];   if (lo < tile) lo = tile;
      int hi = rp[n+1]; if (hi > tile + nrows) hi = tile + nrows;
      lo -= tile; hi -= tile;
      if (lo < hi){
        float m = NM[ln][c];
        for (int r = lo; r < hi; ++r) m = fmaxf(m, H2[r*(C+1) + c]);
        NM[ln][c] = m;
      }
    }
  }
  __syncthreads();
  for (int idx = t; idx < NT*C; idx += 256){
    int ln = idx / C, c = idx - ln*C;
    nodemax[(size_t)(n0+ln)*C + c] = NM[ln][c];
  }
  for (int p = 0; p < NP; ++p){
    __syncthreads();
    #pragma unroll
    for (int i = 0; i < 4; ++i) red[el][grp*4 + i] = s2[p][i];
    __syncthreads();
    if (t < 64){
      float a = 0.f;
      for (int e2 = 0; e2 < 16; ++e2) a += red[e2][t];
      statp[(size_t)blockIdx.x*2*C + p*64 + t] = a;
    }
    __syncthreads();
    #pragma unroll
    for (int i = 0; i < 4; ++i) red[el][grp*4 + i] = q2[p][i];
    __syncthreads();
    if (t < 64){
      float a = 0.f;
      for (int e2 = 0; e2 < 16; ++e2) a += red[e2][t];
      statp[(size_t)blockIdx.x*2*C + C + p*64 + t] = a;
    }
  }
}

// ---------------- BN affine on node maxima ----------------
template<int C>
__global__ void kaffine(const float* __restrict__ nodemax, const int* __restrict__ rp,
                        const float* __restrict__ sc, const float* __restrict__ sh,
                        float* __restrict__ xo, int Nn){
  int i = blockIdx.x*256 + threadIdx.x;
  if (i >= Nn*C) return;
  int n = i / C, c = i - n*C;
  float v = 0.f;
  if (rp[n+1] > rp[n]) v = nodemax[i] * sc[c] + sh[c];
  xo[i] = v;
}

// ---------------- per-graph segment max of x123 ----------------
__global__ void kxg(const float* __restrict__ x1, const float* __restrict__ x2,
                    const float* __restrict__ x3, const int* __restrict__ gptr,
                    float* __restrict__ xg){
  int g = blockIdx.x;
  int c = blockIdx.y * 256 + threadIdx.x;
  if (c >= 448) return;
  int s = gptr[g], e = gptr[g+1];
  float mx = -INFINITY;
  for (int n = s; n < e; ++n){
    float v = (c < 64)  ? x1[(size_t)n*64  + c]
            : (c < 192) ? x2[(size_t)n*128 + (c - 64)]
                        : x3[(size_t)n*256 + (c - 192)];
    mx = fmaxf(mx, v);
  }
  xg[g*448 + c] = (e > s) ? mx : 0.f;
}

// ---------------- m1 ----------------
__launch_bounds__(256)
__global__ void km1(const float* __restrict__ Wf, const float* __restrict__ bias,
                    const float* __restrict__ x1, const float* __restrict__ x2,
                    const float* __restrict__ x3, float* __restrict__ x4p,
                    float* __restrict__ statp, int Nn){
  __shared__ float A[16][449];
  __shared__ float red[16][64];
  int t = threadIdx.x, el = t & 15, grp = t >> 4;
  int r0 = blockIdx.x * 16;
  for (int idx = t; idx < 16*448; idx += 256){
    int r = idx / 448, k = idx - r*448;
    int rr = r0 + r;
    float v = 0.f;
    if (rr < Nn)
      v = (k < 64)  ? x1[(size_t)rr*64  + k]
        : (k < 192) ? x2[(size_t)rr*128 + (k - 64)]
                    : x3[(size_t)rr*256 + (k - 192)];
    A[r][k] = v;
  }
  __syncthreads();
  float sv[4][4], qv[4][4];
  #pragma unroll
  for (int p = 0; p < 4; ++p)
    #pragma unroll
    for (int i = 0; i < 4; ++i){ sv[p][i] = 0.f; qv[p][i] = 0.f; }
  #pragma unroll
  for (int p = 0; p < 4; ++p){
    int c = p*64 + grp*4;
    float acc[4];
    #pragma unroll
    for (int i = 0; i < 4; ++i) acc[i] = bias[c+i];
    #pragma unroll 4
    for (int k = 0; k < 448; ++k){
      float4 w = *reinterpret_cast<const float4*>(&Wf[(size_t)k*256 + c]);
      float a = A[el][k];
      acc[0] = fmaf(a, w.x, acc[0]); acc[1] = fmaf(a, w.y, acc[1]);
      acc[2] = fmaf(a, w.z, acc[2]); acc[3] = fmaf(a, w.w, acc[3]);
    }
    int rr = r0 + el;
    if (rr < Nn){
      float v0 = fmaxf(acc[0],0.f), v1 = fmaxf(acc[1],0.f);
      float v2 = fmaxf(acc[2],0.f), v3 = fmaxf(acc[3],0.f);
      sv[p][0]=v0; sv[p][1]=v1; sv[p][2]=v2; sv[p][3]=v3;
      qv[p][0]=v0*v0; qv[p][1]=v1*v1; qv[p][2]=v2*v2; qv[p][3]=v3*v3;
      float4 o; o.x=v0; o.y=v1; o.z=v2; o.w=v3;
      *reinterpret_cast<float4*>(&x4p[(size_t)rr*256 + c]) = o;
    }
  }
  for (int p = 0; p < 4; ++p){
    __syncthreads();
    #pragma unroll
    for (int i = 0; i < 4; ++i) red[el][grp*4 + i] = sv[p][i];
    __syncthreads();
    if (t < 64){
      float a = 0.f;
      for (int e2 = 0; e2 < 16; ++e2) a += red[e2][t];
      statp[(size_t)blockIdx.x*512 + p*64 + t] = a;
    }
    __syncthreads();
    #pragma unroll
    for (int i = 0; i < 4; ++i) red[el][grp*4 + i] = qv[p][i];
    __syncthreads();
    if (t < 64){
      float a = 0.f;
      for (int e2 = 0; e2 < 16; ++e2) a += red[e2][t];
      statp[(size_t)blockIdx.x*512 + 256 + p*64 + t] = a;
    }
  }
}

// ---------------- m2 + bn8 ----------------
__global__ void m2_mlp(const float* __restrict__ xg, const float* __restrict__ Wf,
                       const float* __restrict__ b, float* __restrict__ u_pre){
  __shared__ float row[448];
  int g = blockIdx.x, t = threadIdx.x;
  for (int k = t; k < 448; k += 256) row[k] = xg[g*448 + k];
  __syncthreads();
  float acc = b[t];
  #pragma unroll 4
  for (int k = 0; k < 448; ++k) acc = fmaf(row[k], Wf[(size_t)k*256 + t], acc);
  u_pre[g*256 + t] = fmaxf(acc, 0.f);
}
__global__ void bn8(const float* __restrict__ u_pre, const float* __restrict__ g,
                    const float* __restrict__ be, float* __restrict__ u_bn){
  int c = threadIdx.x;
  float s = 0.f, q = 0.f;
  for (int r = 0; r < 8; ++r){ float v = u_pre[r*256 + c]; s += v; q += v*v; }
  float m  = s * 0.125f;
  float va = q * 0.125f - m*m;
  float scl = g[c] * rsqrtf(va + 1e-5f);
  float sht = be[c] - m*scl;
  for (int r = 0; r < 8; ++r) u_bn[r*256 + c] = u_pre[r*256 + c]*scl + sht;
}

// ---------------- einsum ----------------
__global__ void keinsum(const float* __restrict__ x4p, const float* __restrict__ sc4,
                        const float* __restrict__ sh4, const float* __restrict__ hmf,
                        const int* __restrict__ gptr, float* __restrict__ x6part){
  int g = blockIdx.x, s32 = blockIdx.y, c = threadIdx.x;
  int s = gptr[g], e = gptr[g+1];
  int len = e - s;
  int per = (len + 31) / 32;
  int n0 = s + s32*per;
  int n1 = n0 + per; if (n1 > e) n1 = e;
  float scl = sc4[c], shf = sh4[c];
  float acc[24];
  #pragma unroll
  for (int i = 0; i < 24; ++i) acc[i] = 0.f;
  __shared__ float hrow[16][24];
  for (int nb = n0; nb < n1; nb += 16){
    int cntn = n1 - nb; if (cntn > 16) cntn = 16;
    __syncthreads();
    for (int i = threadIdx.x; i < cntn*24; i += 256)
      hrow[i/24][i%24] = hmf[(size_t)nb*24 + i];
    __syncthreads();
    for (int j = 0; j < cntn; ++j){
      float a = x4p[(size_t)(nb+j)*256 + c] * scl + shf;
      #pragma unroll
      for (int i = 0; i < 24; ++i) acc[i] = fmaf(a, hrow[j][i], acc[i]);
    }
  }
  #pragma unroll
  for (int i = 0; i < 24; ++i)
    x6part[((size_t)(g*32 + s32)*24 + i)*256 + c] = acc[i];
}
__global__ void keired(const float* __restrict__ x6part, float* __restrict__ x6p){
  int gk = blockIdx.x;
  int g = gk / 24, k = gk - g*24, c = threadIdx.x;
  float a = 0.f;
  for (int s32 = 0; s32 < 32; ++s32)
    a += x6part[((size_t)(g*32 + s32)*24 + k)*256 + c];
  x6p[(size_t)gk*256 + c] = a;
}

// ---------------- final linear + relu + BN (f32 output!) ----------------
__global__ void lin_relu_k(const float* __restrict__ x6p, const float* __restrict__ u_bn,
                           const float* __restrict__ hs, const float* __restrict__ Wf,
                           const float* __restrict__ b, float* __restrict__ x7p){
  __shared__ float row[512];
  int r = blockIdx.x, t = threadIdx.x;
  int g = r / 24, kk = r - g*24;
  row[t]       = x6p[(size_t)r*256 + t];
  row[256 + t] = u_bn[g*256 + t] * hs[g*24 + kk];
  __syncthreads();
  float acc = b[t];
  #pragma unroll 4
  for (int k = 0; k < 512; ++k) acc = fmaf(row[k], Wf[(size_t)k*256 + t], acc);
  x7p[(size_t)r*256 + t] = fmaxf(acc, 0.f);
}
__global__ void final_bn_k(const float* __restrict__ x7p, const float* __restrict__ g,
                           const float* __restrict__ be, float* __restrict__ out){
  int c = threadIdx.x;
  float s = 0.f, q = 0.f;
  for (int r = 0; r < 192; ++r){ float v = x7p[(size_t)r*256 + c]; s += v; q += v*v; }
  const float inv = 1.f / 192.f;
  float m  = s * inv;
  float va = q * inv - m*m;
  float scl = g[c] * rsqrtf(va + 1e-5f);
  float sht = be[c] - m*scl;
  for (int r = 0; r < 192; ++r)
    out[(size_t)r*256 + c] = x7p[(size_t)r*256 + c]*scl + sht;
}

// =================== DIAGNOSTIC SUITE ===================
__global__ void kzero(int* f){ if (threadIdx.x < 8) f[threadIdx.x] = 0; }
__global__ void kerr(float* out, float code){ if (threadIdx.x == 0) out[0] = code; }

template<int CIN, int C, int MODE>
__global__ void kdiag_gcu(const float* __restrict__ W1, const float* __restrict__ b1,
                          const float* __restrict__ W2, const float* __restrict__ b2,
                          const float* __restrict__ s1, const float* __restrict__ h1v,
                          const float* __restrict__ s2, const float* __restrict__ h2v,
                          const float* __restrict__ in0, const float* __restrict__ posf,
                          const float* __restrict__ featf,
                          const int* __restrict__ src, const int* __restrict__ dst, int E,
                          const float* __restrict__ xl, int* flagslot)
{
  constexpr int CP = CIN/2;
  __shared__ int elist[256];
  __shared__ int ecnt;
  __shared__ float a[CIN];
  __shared__ float h1[C];
  __shared__ float mx[C];
  __shared__ float dred[256];
  int t = threadIdx.x;
  if (t == 0) ecnt = 0;
  __syncthreads();
  for (int e = t; e < E; e += 256)
    if (dst[e] == 0){
      int p = atomicAdd(&ecnt, 1);
      if (p < 256) elist[p] = e;
    }
  __syncthreads();
  int ne = ecnt < 256 ? ecnt : 256;
  if (t < C) mx[t] = -INFINITY;
  __syncthreads();
  for (int ei = 0; ei < ne; ++ei){
    int j = src[elist[ei]];
    if (t < CIN){
      int k = t;
      float v;
      if constexpr (MODE == 0){
        v = (k < CP) ? in0[k] : in0[(size_t)j*CP + (k-CP)] - in0[k-CP];
      } else {
        int c = (k < CP) ? k : k - CP;
        float vi = (c < 3) ? posf[c] : featf[c-3];
        if (k < CP) v = vi;
        else {
          float vj = (c < 3) ? posf[(size_t)j*3 + c] : featf[(size_t)j*61 + (c-3)];
          v = vj - vi;
        }
      }
      a[k] = v;
    }
    __syncthreads();
    if (t < C){
      float acc = b1[t];
      for (int k = 0; k < CIN; ++k) acc = fmaf(a[k], W1[(size_t)k*C + t], acc);
      h1[t] = fmaxf(acc, 0.f) * s1[t] + h1v[t];
    }
    __syncthreads();
    if (t < C){
      float acc = b2[t];
      for (int k = 0; k < C; ++k) acc = fmaf(h1[k], W2[(size_t)k*C + t], acc);
      mx[t] = fmaxf(mx[t], fmaxf(acc, 0.f));
    }
    __syncthreads();
  }
  float d = 0.f;
  if (t < C){
    float ref = (ne > 0) ? mx[t]*s2[t] + h2v[t] : 0.f;
    d = fabsf(ref - xl[t]);
  }
  dred[t] = d;
  __syncthreads();
  for (int o = 128; o; o >>= 1){ if (t<o) dred[t]=fmaxf(dred[t],dred[t+o]); __syncthreads(); }
  if (t == 0 && dred[0] > 1e-2f) *flagslot = 1;
}

__global__ void kdiag_m1(const float* __restrict__ Wf, const float* __restrict__ bias,
                         const float* __restrict__ x1, const float* __restrict__ x2,
                         const float* __restrict__ x3, const float* __restrict__ x4p,
                         int* flagslot){
  __shared__ float A[448];
  __shared__ float dred[256];
  int t = threadIdx.x;
  for (int k = t; k < 448; k += 256)
    A[k] = (k < 64) ? x1[k] : (k < 192) ? x2[k-64] : x3[k-192];
  __syncthreads();
  float acc = bias[t];
  for (int k = 0; k < 448; ++k) acc = fmaf(A[k], Wf[(size_t)k*256 + t], acc);
  dred[t] = fabsf(fmaxf(acc, 0.f) - x4p[t]);
  __syncthreads();
  for (int o = 128; o; o >>= 1){ if (t<o) dred[t]=fmaxf(dred[t],dred[t+o]); __syncthreads(); }
  if (t == 0 && dred[0] > 1e-2f) *flagslot = 1;
}

__global__ void kdiag_xg(const float* __restrict__ x1, const float* __restrict__ x2,
                         const float* __restrict__ x3, const int* __restrict__ batch,
                         int Nn, const float* __restrict__ xg, int* flagslot){
  __shared__ float dred[256];
  int t = threadIdx.x;
  float d = 0.f;
  for (int c = t; c < 448; c += 256){
    float mx = -INFINITY; int cg = 0;
    for (int n = 0; n < Nn; ++n){
      if (batch[n] != 0){ if (batch[n] > 0) break; continue; }
      cg = 1;
      float v = (c < 64)  ? x1[(size_t)n*64  + c]
              : (c < 192) ? x2[(size_t)n*128 + (c-64)]
                          : x3[(size_t)n*256 + (c-192)];
      mx = fmaxf(mx, v);
    }
    float ref = cg ? mx : 0.f;
    d = fmaxf(d, fabsf(ref - xg[c]));
  }
  dred[t] = d;
  __syncthreads();
  for (int o = 128; o; o >>= 1){ if (t<o) dred[t]=fmaxf(dred[t],dred[t+o]); __syncthreads(); }
  if (t == 0 && dred[0] > 1e-3f) *flagslot = 1;
}

__global__ void kdiag_ubn(const float* __restrict__ xg, const float* __restrict__ m2w,
                          const float* __restrict__ m2b, const float* __restrict__ m2g,
                          const float* __restrict__ m2be, const float* __restrict__ u_bn,
                          int* flagslot){
  __shared__ float dred[256];
  int t = threadIdx.x;
  float u[8];
  for (int r = 0; r < 8; ++r){
    float acc = m2b[t];
    for (int k = 0; k < 448; ++k) acc = fmaf(xg[r*448 + k], m2w[(size_t)k*256 + t], acc);
    u[r] = fmaxf(acc, 0.f);
  }
  float s = 0.f, q = 0.f;
  for (int r = 0; r < 8; ++r){ s += u[r]; q += u[r]*u[r]; }
  float m  = s * 0.125f;
  float va = q * 0.125f - m*m;
  float scl = m2g[t] * rsqrtf(va + 1e-5f);
  float sht = m2be[t] - m*scl;
  dred[t] = fabsf(u[0]*scl + sht - u_bn[t]);
  __syncthreads();
  for (int o = 128; o; o >>= 1){ if (t<o) dred[t]=fmaxf(dred[t],dred[t+o]); __syncthreads(); }
  if (t == 0 && dred[0] > 5e-2f) *flagslot = 1;
}

__global__ void kdiag_eins(const float* __restrict__ hmf, const int* __restrict__ batch,
                           int Nn, const float* __restrict__ x4p, const float* __restrict__ sc4,
                           const float* __restrict__ sh4, const float* __restrict__ hs,
                           const float* __restrict__ x6p, int* flagslot){
  __shared__ float dred[256];
  int t = threadIdx.x;
  float dh = 0.f;
  if (t < 24){
    float s = 0.f;
    for (int n = 0; n < Nn && batch[n] == 0; ++n) s += hmf[(size_t)n*24 + t];
    dh = fabsf(s - hs[t]);
  }
  float acc = 0.f;
  for (int n = 0; n < Nn && batch[n] == 0; ++n)
    acc = fmaf(hmf[(size_t)n*24 + 0], x4p[(size_t)n*256 + t]*sc4[t] + sh4[t], acc);
  float d6 = fabsf(acc - x6p[t]);
  dred[t] = fmaxf(dh, d6);
  __syncthreads();
  for (int o = 128; o; o >>= 1){ if (t<o) dred[t]=fmaxf(dred[t],dred[t+o]); __syncthreads(); }
  if (t == 0 && dred[0] > 0.5f) *flagslot = 1;
}

__global__ void kdiag_fin(const float* __restrict__ x6p, const float* __restrict__ u_bn,
                          const float* __restrict__ hs, const float* __restrict__ linw,
                          const float* __restrict__ linb, const float* __restrict__ x7p,
                          const float* __restrict__ bng, const float* __restrict__ bnb,
                          const float* __restrict__ out, int* flagslot){
  __shared__ float row[512];
  __shared__ float dred[256];
  int t = threadIdx.x;
  row[t]       = x6p[t];
  row[256 + t] = u_bn[t] * hs[0];
  __syncthreads();
  float acc = linb[t];
  for (int k = 0; k < 512; ++k) acc = fmaf(row[k], linw[(size_t)k*256 + t], acc);
  float dlin = fabsf(fmaxf(acc, 0.f) - x7p[t]);
  float s = 0.f, q = 0.f;
  for (int r = 0; r < 192; ++r){ float v = x7p[(size_t)r*256 + t]; s += v; q += v*v; }
  float m  = s / 192.f;
  float va = q / 192.f - m*m;
  float scl = bng[t] * rsqrtf(va + 1e-5f);
  float sht = bnb[t] - m*scl;
  float dout = fabsf(x7p[t]*scl + sht - out[t]);
  dred[t] = fmaxf(dlin * 0.25f, dout);
  __syncthreads();
  for (int o = 128; o; o >>= 1){ if (t<o) dred[t]=fmaxf(dred[t],dred[t+o]); __syncthreads(); }
  if (t == 0 && dred[0] > 0.05f) *flagslot = 1;
}

__global__ void kcode(const int* __restrict__ f, float* __restrict__ out){
  if (threadIdx.x == 0){
    int code = 0;
    for (int i = 0; i < 8; ++i) if (f[i]) code |= (1 << i);
    if (code) out[0] = 4096.f * (1.f + (float)code);
  }
}

extern "C" void kernel_launch(void* const* d_in, const int* in_sizes, int n_in,
                              void* d_out, int out_size, void* d_ws, size_t ws_size,
                              hipStream_t stream)
{
  const int N = in_sizes[0] / 3;
  const int E = in_sizes[3] / 2;
  float* outf = (float*)d_out;

  // ---- host-side input-map verification (in_sizes is host memory) ----
  {
    const int co_[3] = {64,128,256};
    int exp41[41];
    exp41[0]=N*3; exp41[1]=N*61; exp41[2]=N*24; exp41[3]=2*E; exp41[4]=N;
    int idx=5;
    for (int i=0;i<3;++i){
      int ci = (i==0)?128:(i==1)?128:256;
      exp41[idx++]=ci*co_[i]; exp41[idx++]=co_[i]; exp41[idx++]=co_[i]; exp41[idx++]=co_[i];
      exp41[idx++]=co_[i]*co_[i]; exp41[idx++]=co_[i]; exp41[idx++]=co_[i]; exp41[idx++]=co_[i];
    }
    for (int r=0;r<2;++r){ exp41[idx++]=448*256; exp41[idx++]=256; exp41[idx++]=256; exp41[idx++]=256; }
    exp41[idx++]=512*256; exp41[idx++]=256; exp41[idx++]=256; exp41[idx++]=256;
    int bad = -1;
    if (n_in != 41) bad = 99;
    else for (int i=0;i<41;++i) if (in_sizes[i] != exp41[i]){ bad = i; break; }
    if (bad >= 0){
      kerr<<<1, 64, 0, stream>>>(outf, 100000.f + (float)bad);
      return;
    }
  }

  const int*  tei   = (const int*)d_in[3];
  const int*  batch = (const int*)d_in[4];
  const int*  srcp  = tei;
  const int*  dstp  = tei + E;

  char* base = (char*)d_ws;
  size_t off = 0;
  auto alloc = [&](size_t bytes) -> void* {
    void* p = base + off;
    off = (off + bytes + 255) & ~((size_t)255);
    return p;
  };

  int* flag = (int*)alloc(256);
  int* dflags = (int*)alloc(256);

  float* posf  = (float*)alloc((size_t)N*3*4);
  float* featf = (float*)alloc((size_t)N*61*4);
  float* hmf   = (float*)alloc((size_t)N*24*4);
  float* w1f[3]; float* w2f[3];
  float* b1f[3]; float* g1f[3]; float* be1f[3];
  float* b2ff[3]; float* g2f[3]; float* be2f[3];
  float* s1a[3]; float* h1a[3]; float* s2a[3]; float* h2a[3];
  const int cin1[3] = {128, 128, 256};
  const int co[3]   = {64, 128, 256};
  for (int i = 0; i < 3; ++i){
    w1f[i]  = (float*)alloc((size_t)cin1[i]*co[i]*4);
    w2f[i]  = (float*)alloc((size_t)co[i]*co[i]*4);
    b1f[i]  = (float*)alloc(co[i]*4);
    g1f[i]  = (float*)alloc(co[i]*4);
    be1f[i] = (float*)alloc(co[i]*4);
    b2ff[i] = (float*)alloc(co[i]*4);
    g2f[i]  = (float*)alloc(co[i]*4);
    be2f[i] = (float*)alloc(co[i]*4);
    s1a[i]  = (float*)alloc(co[i]*4);
    h1a[i]  = (float*)alloc(co[i]*4);
    s2a[i]  = (float*)alloc(co[i]*4);
    h2a[i]  = (float*)alloc(co[i]*4);
  }
  float* m1wf = (float*)alloc(448*256*4);
  float* m1bf = (float*)alloc(256*4);
  float* m1gf = (float*)alloc(256*4);
  float* m1bef= (float*)alloc(256*4);
  float* m2wf = (float*)alloc(448*256*4);
  float* m2bf = (float*)alloc(256*4);
  float* m2gf = (float*)alloc(256*4);
  float* m2bef= (float*)alloc(256*4);
  float* linwf= (float*)alloc(512*256*4);
  float* linbf= (float*)alloc(256*4);
  float* bngf = (float*)alloc(256*4);
  float* bnbf = (float*)alloc(256*4);

  float* x1 = (float*)alloc((size_t)N*64*4);
  float* x2 = (float*)alloc((size_t)N*128*4);
  float* x3 = (float*)alloc((size_t)N*256*4);
  float* nodemax = (float*)alloc((size_t)N*256*4);
  float* x4p = nodemax;

  float* statp = (float*)alloc((size_t)3200*512*4);
  int* eidx = (int*)alloc((size_t)E*4);
  int* rp   = (int*)alloc((size_t)(N+1)*4);
  int* cnt  = (int*)alloc((size_t)N*4);
  int* gptr = (int*)alloc(16*4);

  float* gs  = (float*)alloc(256*4);
  float* gq  = (float*)alloc(256*4);
  float* sc4 = (float*)alloc(256*4); float* sh4 = (float*)alloc(256*4);
  float* u_pre = (float*)alloc(8*256*4);
  float* u_bn  = (float*)alloc(8*256*4);
  float* hs    = (float*)alloc(192*4);
  float* xg    = (float*)alloc(8*448*4);
  float* x6part= (float*)alloc((size_t)8*32*24*256*4);
  float* x6p   = (float*)alloc((size_t)192*256*4);
  float* x7p   = (float*)alloc((size_t)192*256*4);
  (void)ws_size; (void)out_size;

  kdetect<<<1, 256, 0, stream>>>((const unsigned short*)d_in[0], flag);
  CTab tab;
  int ti = 0;
  auto add = [&](int idx, float* dstp_, int n){ tab.e[ti].s = d_in[idx]; tab.e[ti].d = dstp_; tab.e[ti].n = n; ++ti; };
  add(0, posf,  N*3);
  add(1, featf, N*61);
  add(2, hmf,   N*24);
  for (int i = 0; i < 3; ++i){
    int b0 = 5 + i*8;
    add(b0+0, w1f[i],  cin1[i]*co[i]);
    add(b0+1, b1f[i],  co[i]);
    add(b0+2, g1f[i],  co[i]);
    add(b0+3, be1f[i], co[i]);
    add(b0+4, w2f[i],  co[i]*co[i]);
    add(b0+5, b2ff[i], co[i]);
    add(b0+6, g2f[i],  co[i]);
    add(b0+7, be2f[i], co[i]);
  }
  add(29, m1wf, 448*256); add(30, m1bf, 256); add(31, m1gf, 256); add(32, m1bef, 256);
  add(33, m2wf, 448*256); add(34, m2bf, 256); add(35, m2gf, 256); add(36, m2bef, 256);
  add(37, linwf, 512*256); add(38, linbf, 256); add(39, bngf, 256); add(40, bnbf, 256);
  kconv<<<dim3(64, 39), 256, 0, stream>>>(tab, flag);

  kgptr<<<1, 64, 0, stream>>>(batch, N, gptr);
  khs<<<8, 256, 0, stream>>>(hmf, gptr, hs);
  ksort<<<1, 256, 0, stream>>>(dstp, E, N, cnt, rp, eidx);

  const int NBK1 = 1024;
  const int NBKF = N / 16;
  const float invE = 1.f / (float)E;

  // GCU1
  kstats1<128,64,3><<<NBK1, 256, 0, stream>>>(w1f[0], b1f[0], nullptr, posf, featf,
      srcp, dstp, E, statp);
  kstatred<<<64, 256, 0, stream>>>(statp, NBK1, 64, gs, gq);
  finalize_bn<<<1, 64, 0, stream>>>(gs, gq, g1f[0], be1f[0], invE, s1a[0], h1a[0]);
  kfused<128,64,32,3><<<NBKF, 256, 0, stream>>>(w1f[0], b1f[0], w2f[0], b2ff[0],
      s1a[0], h1a[0], nullptr, posf, featf, srcp, dstp, eidx, rp, nodemax, statp);
  kstatred<<<64, 256, 0, stream>>>(statp, NBKF, 64, gs, gq);
  finalize_bn<<<1, 64, 0, stream>>>(gs, gq, g2f[0], be2f[0], invE, s2a[0], h2a[0]);
  kaffine<64><<<(N*64 + 255)/256, 256, 0, stream>>>(nodemax, rp, s2a[0], h2a[0], x1, N);

  // GCU2
  kstats1<128,128,0><<<NBK1, 256, 0, stream>>>(w1f[1], b1f[1], x1, nullptr, nullptr,
      srcp, dstp, E, statp);
  kstatred<<<128, 256, 0, stream>>>(statp, NBK1, 128, gs, gq);
  finalize_bn<<<1, 128, 0, stream>>>(gs, gq, g1f[1], be1f[1], invE, s1a[1], h1a[1]);
  kfused<128,128,32,0><<<NBKF, 256, 0, stream>>>(w1f[1], b1f[1], w2f[1], b2ff[1],
      s1a[1], h1a[1], x1, nullptr, nullptr, srcp, dstp, eidx, rp, nodemax, statp);
  kstatred<<<128, 256, 0, stream>>>(statp, NBKF, 128, gs, gq);
  finalize_bn<<<1, 128, 0, stream>>>(gs, gq, g2f[1], be2f[1], invE, s2a[1], h2a[1]);
  kaffine<128><<<(N*128 + 255)/256, 256, 0, stream>>>(nodemax, rp, s2a[1], h2a[1], x2, N);

  // GCU3
  kstats1<256,256,0><<<NBK1, 256, 0, stream>>>(w1f[2], b1f[2], x2, nullptr, nullptr,
      srcp, dstp, E, statp);
  kstatred<<<256, 256, 0, stream>>>(statp, NBK1, 256, gs, gq);
  finalize_bn<<<1, 256, 0, stream>>>(gs, gq, g1f[2], be1f[2], invE, s1a[2], h1a[2]);
  kfused<256,256,16,0><<<NBKF, 256, 0, stream>>>(w1f[2], b1f[2], w2f[2], b2ff[2],
      s1a[2], h1a[2], x2, nullptr, nullptr, srcp, dstp, eidx, rp, nodemax, statp);
  kstatred<<<256, 256, 0, stream>>>(statp, NBKF, 256, gs, gq);
  finalize_bn<<<1, 256, 0, stream>>>(gs, gq, g2f[2], be2f[2], invE, s2a[2], h2a[2]);
  kaffine<256><<<(N*256 + 255)/256, 256, 0, stream>>>(nodemax, rp, s2a[2], h2a[2], x3, N);

  kxg<<<dim3(8, 2), 256, 0, stream>>>(x1, x2, x3, gptr, xg);

  km1<<<NBKF, 256, 0, stream>>>(m1wf, m1bf, x1, x2, x3, x4p, statp, N);
  kstatred<<<256, 256, 0, stream>>>(statp, NBKF, 256, gs, gq);
  finalize_bn<<<1, 256, 0, stream>>>(gs, gq, m1gf, m1bef, 1.f/(float)N, sc4, sh4);

  m2_mlp<<<8, 256, 0, stream>>>(xg, m2wf, m2bf, u_pre);
  bn8<<<1, 256, 0, stream>>>(u_pre, m2gf, m2bef, u_bn);

  keinsum<<<dim3(8, 32), 256, 0, stream>>>(x4p, sc4, sh4, hmf, gptr, x6part);
  keired<<<192, 256, 0, stream>>>(x6part, x6p);

  lin_relu_k<<<192, 256, 0, stream>>>(x6p, u_bn, hs, linwf, linbf, x7p);
  final_bn_k<<<1, 256, 0, stream>>>(x7p, bngf, bnbf, outf);

  // ---- diagnostics (write out[0] ONLY on mismatch) ----
  kzero<<<1, 64, 0, stream>>>(dflags);
  kdiag_gcu<128,64,3><<<1, 256, 0, stream>>>(w1f[0], b1f[0], w2f[0], b2ff[0],
      s1a[0], h1a[0], s2a[0], h2a[0], nullptr, posf, featf, srcp, dstp, E, x1, dflags+0);
  kdiag_gcu<128,128,0><<<1, 256, 0, stream>>>(w1f[1], b1f[1], w2f[1], b2ff[1],
      s1a[1], h1a[1], s2a[1], h2a[1], x1, nullptr, nullptr, srcp, dstp, E, x2, dflags+1);
  kdiag_gcu<256,256,0><<<1, 256, 0, stream>>>(w1f[2], b1f[2], w2f[2], b2ff[2],
      s1a[2], h1a[2], s2a[2], h2a[2], x2, nullptr, nullptr, srcp, dstp, E, x3, dflags+2);
  kdiag_m1<<<1, 256, 0, stream>>>(m1wf, m1bf, x1, x2, x3, x4p, dflags+3);
  kdiag_xg<<<1, 256, 0, stream>>>(x1, x2, x3, batch, N, xg, dflags+4);
  kdiag_ubn<<<1, 256, 0, stream>>>(xg, m2wf, m2bf, m2gf, m2bef, u_bn, dflags+5);
  kdiag_eins<<<1, 256, 0, stream>>>(hmf, batch, N, x4p, sc4, sh4, hs, x6p, dflags+6);
  kdiag_fin<<<1, 256, 0, stream>>>(x6p, u_bn, hs, linwf, linbf, x7p, bngf, bnbf,
      outf, dflags+7);
  kcode<<<1, 64, 0, stream>>>(dflags, outf);
}

// Round 10
// 12635.506 us; speedup vs baseline: 2.1381x; 2.1381x over previous
//
#include <hip/hip_runtime.h>
#include <hip/hip_bf16.h>
#include <cstdint>

using bf16 = __hip_bfloat16;
#define DI __device__ __forceinline__

DI float b2f(bf16 v){ return __bfloat162float(v); }
DI float us2f(unsigned short u){ bf16 t; *reinterpret_cast<unsigned short*>(&t) = u; return __bfloat162float(t); }

// R10: first optimization round on the R9 PASS (27.0 ms, absmax 0.0156).
//  - diagnostics removed (kdiag_xg alone was a 1-block full-N scan)
//  - kxg parallelized: (8 graphs x 32 chunks) partial-max + reduce
//  - counting sort parallelized to 64 blocks (khist/kcnt/kpre/scan/kscatter)
//  - kfused/kstats1: all column-groups accumulated in one k-pass (16 acc/thread)
//    to raise ILP; was NP passes of 4 FMA per W-load (VALUBusy 14.5%).
// Output is FLOAT32. LDS atomics only (no global atomics - R2 lesson).

// ---------------- dtype detection on pos (~N(0,1)) ----------------
__global__ void kdetect(const unsigned short* __restrict__ pos_u, int* __restrict__ flag){
  __shared__ int cE, cO;
  if (threadIdx.x == 0){ cE = 0; cO = 0; }
  __syncthreads();
  int pe = 0, po = 0;
  for (int i = threadIdx.x; i < 2048; i += 256){
    float ve = fabsf(us2f(pos_u[2*i]));
    float vo = fabsf(us2f(pos_u[2*i + 1]));
    if (ve > 1e-4f && ve < 50.f) pe++;
    if (vo > 1e-4f && vo < 50.f) po++;
  }
  atomicAdd(&cE, pe);
  atomicAdd(&cO, po);
  __syncthreads();
  if (threadIdx.x == 0)
    flag[0] = (2*cE < cO) ? 1 : 0;   // 1 => inputs are f32
}

// ---------------- normalize all float inputs to f32 ----------------
struct CEnt { const void* s; float* d; int n; };
struct CTab { CEnt e[39]; };
__global__ void kconv(CTab tab, const int* __restrict__ flag){
  CEnt en = tab.e[blockIdx.y];
  const bool isf32 = (flag[0] != 0);
  for (int i = blockIdx.x*256 + threadIdx.x; i < en.n; i += gridDim.x*256)
    en.d[i] = isf32 ? ((const float*)en.s)[i] : b2f(((const bf16*)en.s)[i]);
}

// ---------------- graph partition ----------------
__global__ void kgptr(const int* __restrict__ batch, int Nn, int* __restrict__ gptr){
  int g = threadIdx.x;
  if (g > 8) return;
  if (g == 8){ gptr[8] = Nn; return; }
  int lo = 0, hi = Nn;
  while (lo < hi){ int mid = (lo + hi) >> 1; if (batch[mid] < g) lo = mid + 1; else hi = mid; }
  gptr[g] = lo;
}

// ---------------- per-graph heatmap column sums ----------------
__global__ void khs(const float* __restrict__ hmf, const int* __restrict__ gptr,
                    float* __restrict__ hs){
  int g = blockIdx.x;
  int lane = threadIdx.x % 24, slice = threadIdx.x / 24;
  __shared__ float part[10][24];
  if (threadIdx.x < 240){
    int s = gptr[g], e = gptr[g+1];
    float acc = 0.f;
    for (int n = s + slice; n < e; n += 10) acc += hmf[(size_t)n*24 + lane];
    part[slice][lane] = acc;
  }
  __syncthreads();
  if (threadIdx.x < 24){
    float a = 0.f;
    for (int i = 0; i < 10; ++i) a += part[i][threadIdx.x];
    hs[g*24 + threadIdx.x] = a;
  }
}

// ---------------- parallel counting sort of edges by dst (64 blocks) ----------------
#define NB_SORT 64
#define SORT_BINS 8192
__global__ void khist(const int* __restrict__ dst, int E, int Nn, int* __restrict__ part){
  int b = blockIdx.x;
  int per = (E + NB_SORT - 1) / NB_SORT;
  int s = b*per, e_end = s + per; if (e_end > E) e_end = E;
  __shared__ int h[SORT_BINS];
  for (int base = 0; base < Nn; base += SORT_BINS){
    for (int i = threadIdx.x; i < SORT_BINS; i += 256) h[i] = 0;
    __syncthreads();
    for (int e = s + threadIdx.x; e < e_end; e += 256){
      int d = dst[e] - base;
      if (d >= 0 && d < SORT_BINS) atomicAdd(&h[d], 1);   // LDS atomic
    }
    __syncthreads();
    int lim = Nn - base; if (lim > SORT_BINS) lim = SORT_BINS;
    for (int i = threadIdx.x; i < lim; i += 256) part[(size_t)b*Nn + base + i] = h[i];
    __syncthreads();
  }
}
__global__ void kcnt(const int* __restrict__ part, int Nn, int* __restrict__ cnt){
  int n = blockIdx.x*256 + threadIdx.x; if (n >= Nn) return;
  int s = 0;
  for (int b = 0; b < NB_SORT; ++b) s += part[(size_t)b*Nn + n];
  cnt[n] = s;
}
__global__ void kpre(int* part, int Nn){
  int n = blockIdx.x*256 + threadIdx.x; if (n >= Nn) return;
  int run = 0;
  for (int b = 0; b < NB_SORT; ++b){
    int v = part[(size_t)b*Nn + n];
    part[(size_t)b*Nn + n] = run;
    run += v;
  }
}
__global__ void kscan(const int* __restrict__ cnt, int Nn, int* __restrict__ rp){
  __shared__ int buf[256];
  __shared__ int carry;
  int t = threadIdx.x;
  if (t == 0) carry = 0;
  __syncthreads();
  for (int base = 0; base < Nn; base += 256){
    int v = (base + t < Nn) ? cnt[base + t] : 0;
    buf[t] = v;
    __syncthreads();
    for (int off = 1; off < 256; off <<= 1){
      int x = (t >= off) ? buf[t - off] : 0;
      __syncthreads();
      buf[t] += x;
      __syncthreads();
    }
    if (base + t < Nn) rp[base + t] = carry + buf[t] - v;
    __syncthreads();
    if (t == 255) carry += buf[255];
    __syncthreads();
  }
  if (t == 0) rp[Nn] = carry;
}
__global__ void kscatter(const int* __restrict__ dst, int E, int Nn,
                         const int* __restrict__ part, const int* __restrict__ rp,
                         int* __restrict__ eidx){
  int b = blockIdx.x;
  int per = (E + NB_SORT - 1) / NB_SORT;
  int s = b*per, e_end = s + per; if (e_end > E) e_end = E;
  __shared__ int cur[SORT_BINS];
  for (int base = 0; base < Nn; base += SORT_BINS){
    for (int i = threadIdx.x; i < SORT_BINS; i += 256) cur[i] = 0;
    __syncthreads();
    for (int e = s + threadIdx.x; e < e_end; e += 256){
      int d = dst[e] - base;
      if (d >= 0 && d < SORT_BINS){
        int lr = atomicAdd(&cur[d], 1);                   // LDS atomic
        eidx[rp[base + d] + part[(size_t)b*Nn + base + d] + lr] = e;  // unique slot
      }
    }
    __syncthreads();
  }
}

// ---------------- layer-1 stats-only pass (all column groups per k) ----------------
template<int CIN, int C, int MODE>
__launch_bounds__(256)
__global__ void kstats1(const float* __restrict__ W1, const float* __restrict__ b1,
                        const float* __restrict__ in0, const float* __restrict__ posf,
                        const float* __restrict__ featf, const int* __restrict__ src,
                        const int* __restrict__ dst, int E, float* __restrict__ statp){
  constexpr int NP = C / 64;
  constexpr int CP = CIN / 2;
  __shared__ float A1[32][CIN + 1];
  __shared__ int Si[32], Sj[32];
  __shared__ float red[16][64];
  int t = threadIdx.x, el = t & 15, grp = t >> 4;
  float sv[NP][4], qv[NP][4];
  #pragma unroll
  for (int p = 0; p < NP; ++p)
    #pragma unroll
    for (int i = 0; i < 4; ++i){ sv[p][i] = 0.f; qv[p][i] = 0.f; }

  int ntiles = (E + 31) / 32;
  for (int tt = blockIdx.x; tt < ntiles; tt += gridDim.x){
    int tile = tt * 32;
    int nrows = E - tile; if (nrows > 32) nrows = 32;
    __syncthreads();
    if (t < 32){
      if (t < nrows){ Si[t] = dst[tile + t]; Sj[t] = src[tile + t]; }
      else { Si[t] = 0; Sj[t] = 0; }
    }
    __syncthreads();
    for (int idx = t; idx < 32*CIN; idx += 256){
      int r = idx / CIN, k = idx - r*CIN;
      float v = 0.f;
      if (r < nrows){
        if constexpr (MODE == 0){
          int i = Si[r], j = Sj[r];
          v = (k < CP) ? in0[(size_t)i*CP + k]
                       : in0[(size_t)j*CP + (k-CP)] - in0[(size_t)i*CP + (k-CP)];
        } else {
          int i = Si[r], j = Sj[r];
          int c = (k < CP) ? k : (k - CP);
          float vi = (c < 3) ? posf[(size_t)i*3 + c] : featf[(size_t)i*61 + (c-3)];
          if (k < CP) v = vi;
          else {
            float vj = (c < 3) ? posf[(size_t)j*3 + c] : featf[(size_t)j*61 + (c-3)];
            v = vj - vi;
          }
        }
      }
      A1[r][k] = v;
    }
    __syncthreads();
    float acc[NP][2][4];
    #pragma unroll
    for (int p = 0; p < NP; ++p)
      #pragma unroll
      for (int i = 0; i < 4; ++i){ float b = b1[p*64 + grp*4 + i]; acc[p][0][i] = b; acc[p][1][i] = b; }
    #pragma unroll 2
    for (int k = 0; k < CIN; ++k){
      float a0 = A1[el][k], a1 = A1[el+16][k];
      #pragma unroll
      for (int p = 0; p < NP; ++p){
        float4 w = *reinterpret_cast<const float4*>(&W1[(size_t)k*C + p*64 + grp*4]);
        acc[p][0][0] = fmaf(a0, w.x, acc[p][0][0]); acc[p][0][1] = fmaf(a0, w.y, acc[p][0][1]);
        acc[p][0][2] = fmaf(a0, w.z, acc[p][0][2]); acc[p][0][3] = fmaf(a0, w.w, acc[p][0][3]);
        acc[p][1][0] = fmaf(a1, w.x, acc[p][1][0]); acc[p][1][1] = fmaf(a1, w.y, acc[p][1][1]);
        acc[p][1][2] = fmaf(a1, w.z, acc[p][1][2]); acc[p][1][3] = fmaf(a1, w.w, acc[p][1][3]);
      }
    }
    #pragma unroll
    for (int p = 0; p < NP; ++p)
      #pragma unroll
      for (int q = 0; q < 2; ++q){
        int row = el + q*16;
        if (row < nrows){
          #pragma unroll
          for (int i = 0; i < 4; ++i){
            float v = fmaxf(acc[p][q][i], 0.f);
            sv[p][i] += v; qv[p][i] += v*v;
          }
        }
      }
  }
  for (int p = 0; p < NP; ++p){
    __syncthreads();
    #pragma unroll
    for (int i = 0; i < 4; ++i) red[el][grp*4 + i] = sv[p][i];
    __syncthreads();
    if (t < 64){
      float a = 0.f;
      for (int e2 = 0; e2 < 16; ++e2) a += red[e2][t];
      statp[(size_t)blockIdx.x*2*C + p*64 + t] = a;
    }
    __syncthreads();
    #pragma unroll
    for (int i = 0; i < 4; ++i) red[el][grp*4 + i] = qv[p][i];
    __syncthreads();
    if (t < 64){
      float a = 0.f;
      for (int e2 = 0; e2 < 16; ++e2) a += red[e2][t];
      statp[(size_t)blockIdx.x*2*C + C + p*64 + t] = a;
    }
  }
}

// ---------------- stats reduce + BN finalize ----------------
__global__ void kstatred(const float* __restrict__ statp, int nblk, int C,
                         float* __restrict__ gs, float* __restrict__ gq){
  int c = blockIdx.x;
  float s = 0.f, q = 0.f;
  for (int b = threadIdx.x; b < nblk; b += 256){
    s += statp[(size_t)b*2*C + c];
    q += statp[(size_t)b*2*C + C + c];
  }
  __shared__ float ls[256], lq[256];
  ls[threadIdx.x] = s; lq[threadIdx.x] = q;
  __syncthreads();
  for (int o = 128; o; o >>= 1){
    if (threadIdx.x < o){ ls[threadIdx.x] += ls[threadIdx.x+o]; lq[threadIdx.x] += lq[threadIdx.x+o]; }
    __syncthreads();
  }
  if (threadIdx.x == 0){ gs[c] = ls[0]; gq[c] = lq[0]; }
}
__global__ void finalize_bn(const float* __restrict__ gs, const float* __restrict__ gq,
                            const float* __restrict__ g, const float* __restrict__ be,
                            float invR, float* __restrict__ sc, float* __restrict__ sh){
  int c = threadIdx.x;
  float m  = gs[c] * invR;
  float va = gq[c] * invR - m*m;
  float s  = g[c] * rsqrtf(va + 1e-5f);
  sc[c] = s;
  sh[c] = be[c] - m*s;
}

// ---------------- fused GCU (all column groups per k) ----------------
template<int CIN, int C, int TE, int MODE>
__launch_bounds__(256)
__global__ void kfused(const float* __restrict__ W1, const float* __restrict__ b1,
                       const float* __restrict__ W2, const float* __restrict__ b2,
                       const float* __restrict__ sc1, const float* __restrict__ sh1,
                       const float* __restrict__ in0, const float* __restrict__ posf,
                       const float* __restrict__ featf,
                       const int* __restrict__ src, const int* __restrict__ dst,
                       const int* __restrict__ eidx, const int* __restrict__ rp,
                       float* __restrict__ nodemax, float* __restrict__ statp)
{
  constexpr int NT  = 16;
  constexpr int EPL = TE / 16;
  constexpr int NP  = C / 64;
  constexpr int CP  = CIN / 2;
  __shared__ float A1[TE][CIN + 1];
  __shared__ float H1[TE][C + 1];
  __shared__ float NM[NT][C];
  __shared__ float red[16][64];
  __shared__ int Si[TE], Sj[TE];
  float* H2 = &A1[0][0];

  int t = threadIdx.x, el = t & 15, grp = t >> 4;
  int n0 = blockIdx.x * NT;
  int e_begin = rp[n0];
  int e_end   = rp[n0 + NT];

  for (int i = t; i < NT*C; i += 256) (&NM[0][0])[i] = -INFINITY;

  float s2[NP][4], q2[NP][4];
  #pragma unroll
  for (int p = 0; p < NP; ++p)
    #pragma unroll
    for (int i = 0; i < 4; ++i){ s2[p][i] = 0.f; q2[p][i] = 0.f; }

  for (int tile = e_begin; tile < e_end; tile += TE){
    int nrows = e_end - tile; if (nrows > TE) nrows = TE;
    __syncthreads();
    if (t < TE){
      if (t < nrows){ int e = eidx[tile + t]; Si[t] = dst[e]; Sj[t] = src[e]; }
      else { Si[t] = 0; Sj[t] = 0; }
    }
    __syncthreads();
    for (int idx = t; idx < TE*CIN; idx += 256){
      int r = idx / CIN, k = idx - r*CIN;
      float v = 0.f;
      if (r < nrows){
        if constexpr (MODE == 0){
          int i = Si[r], j = Sj[r];
          v = (k < CP) ? in0[(size_t)i*CP + k]
                       : in0[(size_t)j*CP + (k-CP)] - in0[(size_t)i*CP + (k-CP)];
        } else {
          int i = Si[r], j = Sj[r];
          int c = (k < CP) ? k : (k - CP);
          float vi = (c < 3) ? posf[(size_t)i*3 + c] : featf[(size_t)i*61 + (c-3)];
          if (k < CP) v = vi;
          else {
            float vj = (c < 3) ? posf[(size_t)j*3 + c] : featf[(size_t)j*61 + (c-3)];
            v = vj - vi;
          }
        }
      }
      A1[r][k] = v;
    }
    __syncthreads();
    // layer-1: relu + BN1 affine -> H1
    {
      float acc[NP][EPL][4];
      #pragma unroll
      for (int p = 0; p < NP; ++p)
        #pragma unroll
        for (int i = 0; i < 4; ++i){
          float b = b1[p*64 + grp*4 + i];
          #pragma unroll
          for (int q = 0; q < EPL; ++q) acc[p][q][i] = b;
        }
      #pragma unroll 2
      for (int k = 0; k < CIN; ++k){
        float a[EPL];
        #pragma unroll
        for (int q = 0; q < EPL; ++q) a[q] = A1[el + q*16][k];
        #pragma unroll
        for (int p = 0; p < NP; ++p){
          float4 w = *reinterpret_cast<const float4*>(&W1[(size_t)k*C + p*64 + grp*4]);
          #pragma unroll
          for (int q = 0; q < EPL; ++q){
            acc[p][q][0] = fmaf(a[q], w.x, acc[p][q][0]);
            acc[p][q][1] = fmaf(a[q], w.y, acc[p][q][1]);
            acc[p][q][2] = fmaf(a[q], w.z, acc[p][q][2]);
            acc[p][q][3] = fmaf(a[q], w.w, acc[p][q][3]);
          }
        }
      }
      #pragma unroll
      for (int p = 0; p < NP; ++p)
        #pragma unroll
        for (int q = 0; q < EPL; ++q){
          int row = el + q*16;
          if (row < nrows){
            int c = p*64 + grp*4;
            #pragma unroll
            for (int i = 0; i < 4; ++i)
              H1[row][c+i] = fmaxf(acc[p][q][i], 0.f) * sc1[c+i] + sh1[c+i];
          }
        }
    }
    __syncthreads();
    // layer-2: raw relu -> H2 + stats
    {
      float acc[NP][EPL][4];
      #pragma unroll
      for (int p = 0; p < NP; ++p)
        #pragma unroll
        for (int i = 0; i < 4; ++i){
          float b = b2[p*64 + grp*4 + i];
          #pragma unroll
          for (int q = 0; q < EPL; ++q) acc[p][q][i] = b;
        }
      #pragma unroll 2
      for (int k = 0; k < C; ++k){
        float a[EPL];
        #pragma unroll
        for (int q = 0; q < EPL; ++q) a[q] = H1[el + q*16][k];
        #pragma unroll
        for (int p = 0; p < NP; ++p){
          float4 w = *reinterpret_cast<const float4*>(&W2[(size_t)k*C + p*64 + grp*4]);
          #pragma unroll
          for (int q = 0; q < EPL; ++q){
            acc[p][q][0] = fmaf(a[q], w.x, acc[p][q][0]);
            acc[p][q][1] = fmaf(a[q], w.y, acc[p][q][1]);
            acc[p][q][2] = fmaf(a[q], w.z, acc[p][q][2]);
            acc[p][q][3] = fmaf(a[q], w.w, acc[p][q][3]);
          }
        }
      }
      #pragma unroll
      for (int p = 0; p < NP; ++p)
        #pragma unroll
        for (int q = 0; q < EPL; ++q){
          int row = el + q*16;
          if (row < nrows){
            int c = p*64 + grp*4;
            #pragma unroll
            for (int i = 0; i < 4; ++i){
              float v = fmaxf(acc[p][q][i], 0.f);
              s2[p][i] += v; q2[p][i] += v*v;
              H2[row*(C+1) + c + i] = v;
            }
          }
        }
    }
    __syncthreads();
    // per-node max update from this tile
    for (int idx = t; idx < NT*C; idx += 256){
      int ln = idx / C, c = idx - ln*C;
      int n = n0 + ln;
      int lo = rp[n];   if (lo < tile) lo = tile;
      int hi = rp[n+1]; if (hi > tile + nrows) hi = tile + nrows;
      lo -= tile; hi -= tile;
      if (lo < hi){
        float m = NM[ln][c];
        for (int r = lo; r < hi; ++r) m = fmaxf(m, H2[r*(C+1) + c]);
        NM[ln][c] = m;
      }
    }
  }
  __syncthreads();
  for (int idx = t; idx < NT*C; idx += 256){
    int ln = idx / C, c = idx - ln*C;
    nodemax[(size_t)(n0+ln)*C + c] = NM[ln][c];
  }
  for (int p = 0; p < NP; ++p){
    __syncthreads();
    #pragma unroll
    for (int i = 0; i < 4; ++i) red[el][grp*4 + i] = s2[p][i];
    __syncthreads();
    if (t < 64){
      float a = 0.f;
      for (int e2 = 0; e2 < 16; ++e2) a += red[e2][t];
      statp[(size_t)blockIdx.x*2*C + p*64 + t] = a;
    }
    __syncthreads();
    #pragma unroll
    for (int i = 0; i < 4; ++i) red[el][grp*4 + i] = q2[p][i];
    __syncthreads();
    if (t < 64){
      float a = 0.f;
      for (int e2 = 0; e2 < 16; ++e2) a += red[e2][t];
      statp[(size_t)blockIdx.x*2*C + C + p*64 + t] = a;
    }
  }
}

// ---------------- BN affine on node maxima ----------------
template<int C>
__global__ void kaffine(const float* __restrict__ nodemax, const int* __restrict__ rp,
                        const float* __restrict__ sc, const float* __restrict__ sh,
                        float* __restrict__ xo, int Nn){
  int i = blockIdx.x*256 + threadIdx.x;
  if (i >= Nn*C) return;
  int n = i / C, c = i - n*C;
  float v = 0.f;
  if (rp[n+1] > rp[n]) v = nodemax[i] * sc[c] + sh[c];
  xo[i] = v;
}

// ---------------- per-graph segment max of x123 (two-phase parallel) ----------------
__global__ void kxg_part(const float* __restrict__ x1, const float* __restrict__ x2,
                         const float* __restrict__ x3, const int* __restrict__ gptr,
                         float* __restrict__ xgpart){
  int g = blockIdx.x, ch = blockIdx.y;   // 32 chunks per graph
  int t = threadIdx.x;
  int s = gptr[g], e = gptr[g+1];
  int len = e - s, per = (len + 31) / 32;
  int n0 = s + ch*per, n1 = n0 + per; if (n1 > e) n1 = e;
  float mx0 = -INFINITY, mx1 = -INFINITY;
  int c0 = t, c1 = t + 256;
  for (int n = n0; n < n1; ++n){
    float v0 = (c0 < 64)  ? x1[(size_t)n*64  + c0]
             : (c0 < 192) ? x2[(size_t)n*128 + (c0 - 64)]
                          : x3[(size_t)n*256 + (c0 - 192)];
    mx0 = fmaxf(mx0, v0);
    if (c1 < 448){
      float v1 = x3[(size_t)n*256 + (c1 - 192)];
      mx1 = fmaxf(mx1, v1);
    }
  }
  xgpart[(size_t)(g*32 + ch)*448 + c0] = mx0;
  if (c1 < 448) xgpart[(size_t)(g*32 + ch)*448 + c1] = mx1;
}
__global__ void kxg_red(const float* __restrict__ xgpart, const int* __restrict__ gptr,
                        float* __restrict__ xg){
  int g = blockIdx.x;
  int c = blockIdx.y * 256 + threadIdx.x;
  if (c >= 448) return;
  float mx = -INFINITY;
  for (int ch = 0; ch < 32; ++ch)
    mx = fmaxf(mx, xgpart[(size_t)(g*32 + ch)*448 + c]);
  xg[g*448 + c] = (gptr[g+1] > gptr[g] && !__builtin_isinf(mx)) ? mx : 0.f;
}

// ---------------- m1 ----------------
__launch_bounds__(256)
__global__ void km1(const float* __restrict__ Wf, const float* __restrict__ bias,
                    const float* __restrict__ x1, const float* __restrict__ x2,
                    const float* __restrict__ x3, float* __restrict__ x4p,
                    float* __restrict__ statp, int Nn){
  __shared__ float A[16][449];
  __shared__ float red[16][64];
  int t = threadIdx.x, el = t & 15, grp = t >> 4;
  int r0 = blockIdx.x * 16;
  for (int idx = t; idx < 16*448; idx += 256){
    int r = idx / 448, k = idx - r*448;
    int rr = r0 + r;
    float v = 0.f;
    if (rr < Nn)
      v = (k < 64)  ? x1[(size_t)rr*64  + k]
        : (k < 192) ? x2[(size_t)rr*128 + (k - 64)]
                    : x3[(size_t)rr*256 + (k - 192)];
    A[r][k] = v;
  }
  __syncthreads();
  float sv[4][4], qv[4][4];
  float acc[4][4];
  #pragma unroll
  for (int p = 0; p < 4; ++p)
    #pragma unroll
    for (int i = 0; i < 4; ++i){
      sv[p][i] = 0.f; qv[p][i] = 0.f;
      acc[p][i] = bias[p*64 + grp*4 + i];
    }
  #pragma unroll 2
  for (int k = 0; k < 448; ++k){
    float a = A[el][k];
    #pragma unroll
    for (int p = 0; p < 4; ++p){
      float4 w = *reinterpret_cast<const float4*>(&Wf[(size_t)k*256 + p*64 + grp*4]);
      acc[p][0] = fmaf(a, w.x, acc[p][0]); acc[p][1] = fmaf(a, w.y, acc[p][1]);
      acc[p][2] = fmaf(a, w.z, acc[p][2]); acc[p][3] = fmaf(a, w.w, acc[p][3]);
    }
  }
  int rr = r0 + el;
  #pragma unroll
  for (int p = 0; p < 4; ++p){
    if (rr < Nn){
      int c = p*64 + grp*4;
      float v0 = fmaxf(acc[p][0],0.f), v1 = fmaxf(acc[p][1],0.f);
      float v2 = fmaxf(acc[p][2],0.f), v3 = fmaxf(acc[p][3],0.f);
      sv[p][0]=v0; sv[p][1]=v1; sv[p][2]=v2; sv[p][3]=v3;
      qv[p][0]=v0*v0; qv[p][1]=v1*v1; qv[p][2]=v2*v2; qv[p][3]=v3*v3;
      float4 o; o.x=v0; o.y=v1; o.z=v2; o.w=v3;
      *reinterpret_cast<float4*>(&x4p[(size_t)rr*256 + c]) = o;
    }
  }
  for (int p = 0; p < 4; ++p){
    __syncthreads();
    #pragma unroll
    for (int i = 0; i < 4; ++i) red[el][grp*4 + i] = sv[p][i];
    __syncthreads();
    if (t < 64){
      float a = 0.f;
      for (int e2 = 0; e2 < 16; ++e2) a += red[e2][t];
      statp[(size_t)blockIdx.x*512 + p*64 + t] = a;
    }
    __syncthreads();
    #pragma unroll
    for (int i = 0; i < 4; ++i) red[el][grp*4 + i] = qv[p][i];
    __syncthreads();
    if (t < 64){
      float a = 0.f;
      for (int e2 = 0; e2 < 16; ++e2) a += red[e2][t];
      statp[(size_t)blockIdx.x*512 + 256 + p*64 + t] = a;
    }
  }
}

// ---------------- m2 + bn8 ----------------
__global__ void m2_mlp(const float* __restrict__ xg, const float* __restrict__ Wf,
                       const float* __restrict__ b, float* __restrict__ u_pre){
  __shared__ float row[448];
  int g = blockIdx.x, t = threadIdx.x;
  for (int k = t; k < 448; k += 256) row[k] = xg[g*448 + k];
  __syncthreads();
  float acc = b[t];
  #pragma unroll 4
  for (int k = 0; k < 448; ++k) acc = fmaf(row[k], Wf[(size_t)k*256 + t], acc);
  u_pre[g*256 + t] = fmaxf(acc, 0.f);
}
__global__ void bn8(const float* __restrict__ u_pre, const float* __restrict__ g,
                    const float* __restrict__ be, float* __restrict__ u_bn){
  int c = threadIdx.x;
  float s = 0.f, q = 0.f;
  for (int r = 0; r < 8; ++r){ float v = u_pre[r*256 + c]; s += v; q += v*v; }
  float m  = s * 0.125f;
  float va = q * 0.125f - m*m;
  float scl = g[c] * rsqrtf(va + 1e-5f);
  float sht = be[c] - m*scl;
  for (int r = 0; r < 8; ++r) u_bn[r*256 + c] = u_pre[r*256 + c]*scl + sht;
}

// ---------------- einsum ----------------
__global__ void keinsum(const float* __restrict__ x4p, const float* __restrict__ sc4,
                        const float* __restrict__ sh4, const float* __restrict__ hmf,
                        const int* __restrict__ gptr, float* __restrict__ x6part){
  int g = blockIdx.x, s32 = blockIdx.y, c = threadIdx.x;
  int s = gptr[g], e = gptr[g+1];
  int len = e - s;
  int per = (len + 31) / 32;
  int n0 = s + s32*per;
  int n1 = n0 + per; if (n1 > e) n1 = e;
  float scl = sc4[c], shf = sh4[c];
  float acc[24];
  #pragma unroll
  for (int i = 0; i < 24; ++i) acc[i] = 0.f;
  __shared__ float hrow[16][24];
  for (int nb = n0; nb < n1; nb += 16){
    int cntn = n1 - nb; if (cntn > 16) cntn = 16;
    __syncthreads();
    for (int i = threadIdx.x; i < cntn*24; i += 256)
      hrow[i/24][i%24] = hmf[(size_t)nb*24 + i];
    __syncthreads();
    for (int j = 0; j < cntn; ++j){
      float a = x4p[(size_t)(nb+j)*256 + c] * scl + shf;
      #pragma unroll
      for (int i = 0; i < 24; ++i) acc[i] = fmaf(a, hrow[j][i], acc[i]);
    }
  }
  #pragma unroll
  for (int i = 0; i < 24; ++i)
    x6part[((size_t)(g*32 + s32)*24 + i)*256 + c] = acc[i];
}
__global__ void keired(const float* __restrict__ x6part, float* __restrict__ x6p){
  int gk = blockIdx.x;
  int g = gk / 24, k = gk - g*24, c = threadIdx.x;
  float a = 0.f;
  for (int s32 = 0; s32 < 32; ++s32)
    a += x6part[((size_t)(g*32 + s32)*24 + k)*256 + c];
  x6p[(size_t)gk*256 + c] = a;
}

// ---------------- final linear + relu + BN (f32 output) ----------------
__global__ void lin_relu_k(const float* __restrict__ x6p, const float* __restrict__ u_bn,
                           const float* __restrict__ hs, const float* __restrict__ Wf,
                           const float* __restrict__ b, float* __restrict__ x7p){
  __shared__ float row[512];
  int r = blockIdx.x, t = threadIdx.x;
  int g = r / 24, kk = r - g*24;
  row[t]       = x6p[(size_t)r*256 + t];
  row[256 + t] = u_bn[g*256 + t] * hs[g*24 + kk];
  __syncthreads();
  float acc = b[t];
  #pragma unroll 4
  for (int k = 0; k < 512; ++k) acc = fmaf(row[k], Wf[(size_t)k*256 + t], acc);
  x7p[(size_t)r*256 + t] = fmaxf(acc, 0.f);
}
__global__ void final_bn_k(const float* __restrict__ x7p, const float* __restrict__ g,
                           const float* __restrict__ be, float* __restrict__ out){
  int c = threadIdx.x;
  float s = 0.f, q = 0.f;
  for (int r = 0; r < 192; ++r){ float v = x7p[(size_t)r*256 + c]; s += v; q += v*v; }
  const float inv = 1.f / 192.f;
  float m  = s * inv;
  float va = q * inv - m*m;
  float scl = g[c] * rsqrtf(va + 1e-5f);
  float sht = be[c] - m*scl;
  for (int r = 0; r < 192; ++r)
    out[(size_t)r*256 + c] = x7p[(size_t)r*256 + c]*scl + sht;
}

__global__ void kerr(float* out, float code){ if (threadIdx.x == 0) out[0] = code; }

extern "C" void kernel_launch(void* const* d_in, const int* in_sizes, int n_in,
                              void* d_out, int out_size, void* d_ws, size_t ws_size,
                              hipStream_t stream)
{
  const int N = in_sizes[0] / 3;
  const int E = in_sizes[3] / 2;
  float* outf = (float*)d_out;

  // ---- host-side input-map verification ----
  {
    const int co_[3] = {64,128,256};
    int exp41[41];
    exp41[0]=N*3; exp41[1]=N*61; exp41[2]=N*24; exp41[3]=2*E; exp41[4]=N;
    int idx=5;
    for (int i=0;i<3;++i){
      int ci = (i==0)?128:(i==1)?128:256;
      exp41[idx++]=ci*co_[i]; exp41[idx++]=co_[i]; exp41[idx++]=co_[i]; exp41[idx++]=co_[i];
      exp41[idx++]=co_[i]*co_[i]; exp41[idx++]=co_[i]; exp41[idx++]=co_[i]; exp41[idx++]=co_[i];
    }
    for (int r=0;r<2;++r){ exp41[idx++]=448*256; exp41[idx++]=256; exp41[idx++]=256; exp41[idx++]=256; }
    exp41[idx++]=512*256; exp41[idx++]=256; exp41[idx++]=256; exp41[idx++]=256;
    int bad = -1;
    if (n_in != 41) bad = 99;
    else for (int i=0;i<41;++i) if (in_sizes[i] != exp41[i]){ bad = i; break; }
    if (bad >= 0){
      kerr<<<1, 64, 0, stream>>>(outf, 100000.f + (float)bad);
      return;
    }
  }

  const int*  tei   = (const int*)d_in[3];
  const int*  batch = (const int*)d_in[4];
  const int*  srcp  = tei;
  const int*  dstp  = tei + E;

  char* base = (char*)d_ws;
  size_t off = 0;
  auto alloc = [&](size_t bytes) -> void* {
    void* p = base + off;
    off = (off + bytes + 255) & ~((size_t)255);
    return p;
  };

  int* flag = (int*)alloc(256);

  float* posf  = (float*)alloc((size_t)N*3*4);
  float* featf = (float*)alloc((size_t)N*61*4);
  float* hmf   = (float*)alloc((size_t)N*24*4);
  float* w1f[3]; float* w2f[3];
  float* b1f[3]; float* g1f[3]; float* be1f[3];
  float* b2ff[3]; float* g2f[3]; float* be2f[3];
  float* s1a[3]; float* h1a[3]; float* s2a[3]; float* h2a[3];
  const int cin1[3] = {128, 128, 256};
  const int co[3]   = {64, 128, 256};
  for (int i = 0; i < 3; ++i){
    w1f[i]  = (float*)alloc((size_t)cin1[i]*co[i]*4);
    w2f[i]  = (float*)alloc((size_t)co[i]*co[i]*4);
    b1f[i]  = (float*)alloc(co[i]*4);
    g1f[i]  = (float*)alloc(co[i]*4);
    be1f[i] = (float*)alloc(co[i]*4);
    b2ff[i] = (float*)alloc(co[i]*4);
    g2f[i]  = (float*)alloc(co[i]*4);
    be2f[i] = (float*)alloc(co[i]*4);
    s1a[i]  = (float*)alloc(co[i]*4);
    h1a[i]  = (float*)alloc(co[i]*4);
    s2a[i]  = (float*)alloc(co[i]*4);
    h2a[i]  = (float*)alloc(co[i]*4);
  }
  float* m1wf = (float*)alloc(448*256*4);
  float* m1bf = (float*)alloc(256*4);
  float* m1gf = (float*)alloc(256*4);
  float* m1bef= (float*)alloc(256*4);
  float* m2wf = (float*)alloc(448*256*4);
  float* m2bf = (float*)alloc(256*4);
  float* m2gf = (float*)alloc(256*4);
  float* m2bef= (float*)alloc(256*4);
  float* linwf= (float*)alloc(512*256*4);
  float* linbf= (float*)alloc(256*4);
  float* bngf = (float*)alloc(256*4);
  float* bnbf = (float*)alloc(256*4);

  float* x1 = (float*)alloc((size_t)N*64*4);
  float* x2 = (float*)alloc((size_t)N*128*4);
  float* x3 = (float*)alloc((size_t)N*256*4);
  float* nodemax = (float*)alloc((size_t)N*256*4);
  float* x4p = nodemax;                          // alias: nodemax dead before km1

  float* statp = (float*)alloc((size_t)3200*512*4);
  int* part = (int*)alloc((size_t)NB_SORT*N*4);  // 12.8 MB
  int* eidx = (int*)alloc((size_t)E*4);
  int* rp   = (int*)alloc((size_t)(N+1)*4);
  int* cnt  = (int*)alloc((size_t)N*4);
  int* gptr = (int*)alloc(16*4);

  float* gs  = (float*)alloc(256*4);
  float* gq  = (float*)alloc(256*4);
  float* sc4 = (float*)alloc(256*4); float* sh4 = (float*)alloc(256*4);
  float* u_pre = (float*)alloc(8*256*4);
  float* u_bn  = (float*)alloc(8*256*4);
  float* hs    = (float*)alloc(192*4);
  float* xg    = (float*)alloc(8*448*4);
  float* xgpart= (float*)alloc((size_t)8*32*448*4);
  float* x6part= (float*)alloc((size_t)8*32*24*256*4);
  float* x6p   = (float*)alloc((size_t)192*256*4);
  float* x7p   = (float*)alloc((size_t)192*256*4);
  (void)ws_size; (void)out_size;

  kdetect<<<1, 256, 0, stream>>>((const unsigned short*)d_in[0], flag);
  CTab tab;
  int ti = 0;
  auto add = [&](int idx, float* dstp_, int n){ tab.e[ti].s = d_in[idx]; tab.e[ti].d = dstp_; tab.e[ti].n = n; ++ti; };
  add(0, posf,  N*3);
  add(1, featf, N*61);
  add(2, hmf,   N*24);
  for (int i = 0; i < 3; ++i){
    int b0 = 5 + i*8;
    add(b0+0, w1f[i],  cin1[i]*co[i]);
    add(b0+1, b1f[i],  co[i]);
    add(b0+2, g1f[i],  co[i]);
    add(b0+3, be1f[i], co[i]);
    add(b0+4, w2f[i],  co[i]*co[i]);
    add(b0+5, b2ff[i], co[i]);
    add(b0+6, g2f[i],  co[i]);
    add(b0+7, be2f[i], co[i]);
  }
  add(29, m1wf, 448*256); add(30, m1bf, 256); add(31, m1gf, 256); add(32, m1bef, 256);
  add(33, m2wf, 448*256); add(34, m2bf, 256); add(35, m2gf, 256); add(36, m2bef, 256);
  add(37, linwf, 512*256); add(38, linbf, 256); add(39, bngf, 256); add(40, bnbf, 256);
  kconv<<<dim3(64, 39), 256, 0, stream>>>(tab, flag);

  kgptr<<<1, 64, 0, stream>>>(batch, N, gptr);
  khs<<<8, 256, 0, stream>>>(hmf, gptr, hs);

  // ---- parallel counting sort of edges by dst ----
  const int gridN = (N + 255)/256;
  khist<<<NB_SORT, 256, 0, stream>>>(dstp, E, N, part);
  kcnt<<<gridN, 256, 0, stream>>>(part, N, cnt);
  kscan<<<1, 256, 0, stream>>>(cnt, N, rp);
  kpre<<<gridN, 256, 0, stream>>>(part, N);
  kscatter<<<NB_SORT, 256, 0, stream>>>(dstp, E, N, part, rp, eidx);

  const int NBK1 = 1024;
  const int NBKF = N / 16;
  const float invE = 1.f / (float)E;

  // GCU1
  kstats1<128,64,3><<<NBK1, 256, 0, stream>>>(w1f[0], b1f[0], nullptr, posf, featf,
      srcp, dstp, E, statp);
  kstatred<<<64, 256, 0, stream>>>(statp, NBK1, 64, gs, gq);
  finalize_bn<<<1, 64, 0, stream>>>(gs, gq, g1f[0], be1f[0], invE, s1a[0], h1a[0]);
  kfused<128,64,32,3><<<NBKF, 256, 0, stream>>>(w1f[0], b1f[0], w2f[0], b2ff[0],
      s1a[0], h1a[0], nullptr, posf, featf, srcp, dstp, eidx, rp, nodemax, statp);
  kstatred<<<64, 256, 0, stream>>>(statp, NBKF, 64, gs, gq);
  finalize_bn<<<1, 64, 0, stream>>>(gs, gq, g2f[0], be2f[0], invE, s2a[0], h2a[0]);
  kaffine<64><<<(N*64 + 255)/256, 256, 0, stream>>>(nodemax, rp, s2a[0], h2a[0], x1, N);

  // GCU2
  kstats1<128,128,0><<<NBK1, 256, 0, stream>>>(w1f[1], b1f[1], x1, nullptr, nullptr,
      srcp, dstp, E, statp);
  kstatred<<<128, 256, 0, stream>>>(statp, NBK1, 128, gs, gq);
  finalize_bn<<<1, 128, 0, stream>>>(gs, gq, g1f[1], be1f[1], invE, s1a[1], h1a[1]);
  kfused<128,128,32,0><<<NBKF, 256, 0, stream>>>(w1f[1], b1f[1], w2f[1], b2ff[1],
      s1a[1], h1a[1], x1, nullptr, nullptr, srcp, dstp, eidx, rp, nodemax, statp);
  kstatred<<<128, 256, 0, stream>>>(statp, NBKF, 128, gs, gq);
  finalize_bn<<<1, 128, 0, stream>>>(gs, gq, g2f[1], be2f[1], invE, s2a[1], h2a[1]);
  kaffine<128><<<(N*128 + 255)/256, 256, 0, stream>>>(nodemax, rp, s2a[1], h2a[1], x2, N);

  // GCU3
  kstats1<256,256,0><<<NBK1, 256, 0, stream>>>(w1f[2], b1f[2], x2, nullptr, nullptr,
      srcp, dstp, E, statp);
  kstatred<<<256, 256, 0, stream>>>(statp, NBK1, 256, gs, gq);
  finalize_bn<<<1, 256, 0, stream>>>(gs, gq, g1f[2], be1f[2], invE, s1a[2], h1a[2]);
  kfused<256,256,16,0><<<NBKF, 256, 0, stream>>>(w1f[2], b1f[2], w2f[2], b2ff[2],
      s1a[2], h1a[2], x2, nullptr, nullptr, srcp, dstp, eidx, rp, nodemax, statp);
  kstatred<<<256, 256, 0, stream>>>(statp, NBKF, 256, gs, gq);
  finalize_bn<<<1, 256, 0, stream>>>(gs, gq, g2f[2], be2f[2], invE, s2a[2], h2a[2]);
  kaffine<256><<<(N*256 + 255)/256, 256, 0, stream>>>(nodemax, rp, s2a[2], h2a[2], x3, N);

  // graph pooling (parallel two-phase)
  kxg_part<<<dim3(8, 32), 256, 0, stream>>>(x1, x2, x3, gptr, xgpart);
  kxg_red<<<dim3(8, 2), 256, 0, stream>>>(xgpart, gptr, xg);

  km1<<<NBKF, 256, 0, stream>>>(m1wf, m1bf, x1, x2, x3, x4p, statp, N);
  kstatred<<<256, 256, 0, stream>>>(statp, NBKF, 256, gs, gq);
  finalize_bn<<<1, 256, 0, stream>>>(gs, gq, m1gf, m1bef, 1.f/(float)N, sc4, sh4);

  m2_mlp<<<8, 256, 0, stream>>>(xg, m2wf, m2bf, u_pre);
  bn8<<<1, 256, 0, stream>>>(u_pre, m2gf, m2bef, u_bn);

  keinsum<<<dim3(8, 32), 256, 0, stream>>>(x4p, sc4, sh4, hmf, gptr, x6part);
  keired<<<192, 256, 0, stream>>>(x6part, x6p);

  lin_relu_k<<<192, 256, 0, stream>>>(x6p, u_bn, hs, linwf, linbf, x7p);
  final_bn_k<<<1, 256, 0, stream>>>(x7p, bngf, bnbf, outf);
}